// Round 4
// baseline (298.702 us; speedup 1.0000x reference)
//
#include <hip/hip_runtime.h>

#define B_ROWS 65536
#define DDIM   256
#define KEMB   1024
#define LRC    0.05f
#define BM 64
#define BN 128

typedef __attribute__((ext_vector_type(8))) _Float16 half8;
typedef __attribute__((ext_vector_type(4))) float f32x4;

// ---- workspace layout (bytes) ----
#define SX_OFF    0u            // 1 MB fp32 [K][D]
#define CNT_OFF   1048576u      // 4 KB int [K]
#define SUMS_OFF  1052672u      // 640 B: [1]=commit,[2]=som,[8..71]=xsq slots
#define ESQ_OFF   1053312u      // 4 KB fp32 [K]
#define CUR_OFF   1057408u      // 4 KB int [K]
#define NMIN_OFF  1061504u      // int [B] = 256 KB
#define ROWS_OFF  1585792u      // 256 KB int [B]
#define EH_OFF    1847936u      // 512 KB f16 [K][D]

static __device__ __forceinline__ unsigned short f2h(float f) {
  _Float16 h = (_Float16)f;
  return *(unsigned short*)&h;
}
static __device__ __forceinline__ float h2f(unsigned short u) {
  _Float16 h = *(_Float16*)&u;
  return (float)h;
}

// ---------------- convert: E->Eh f16 + esq (X conversion now fused into gemm) ----
__global__ __launch_bounds__(256) void convert_kernel(
    const float* __restrict__ E, unsigned short* __restrict__ Eh,
    float* __restrict__ esq) {
  size_t i = (size_t)blockIdx.x * 256 + threadIdx.x;
  size_t off = i * 8;
  const float4 v0 = *(const float4*)(E + off);
  const float4 v1 = *(const float4*)(E + off + 4);
  float f[8] = {v0.x, v0.y, v0.z, v0.w, v1.x, v1.y, v1.z, v1.w};
  unsigned short h[8];
  float part = 0.f;
#pragma unroll
  for (int j = 0; j < 8; ++j) {
    h[j] = f2h(f[j]);
    part += f[j] * f[j];
  }
  *(uint4*)(Eh + off) = *(const uint4*)h;
  float s = part;
  for (int o = 16; o > 0; o >>= 1) s += __shfl_down(s, o, 32);
  if ((threadIdx.x & 31) == 0) esq[i >> 5] = s;
}

// ---------------- A: X-persistent-LDS dist-GEMM, barrier-free K-loop ------------
// Round-3 post-mortem: CU LDS pipe ~90% busy (2 blocks x (32 ds_read + E-stage
// writes) ~ 900cyc/step-pair ~= measured wall). Fix: remove traffic from LDS.
//  * B (E-hi frags) read directly from global per lane (E-hi 512KB = L2-resident;
//    waves 0/2,1/3 + co-resident block read identical addrs -> L1 reuse).
//    -> no sE, no E staging writes, and NO BARRIERS in the 64-step loop: sX is
//    read-only after prologue, compiler pipelines loads across iterations.
//  * X f32->hi/lo f16 conversion fused into prologue (reg-staged, swizzled
//    ds_write_b128) - deletes 64MB Xhl HBM writes + 42MB re-reads + a kernel.
// Bit-identical math vs round 3: same f2h decomposition, same E bytes, same
// MFMA order, same argmin tie-breaks.
__global__ __launch_bounds__(256, 2) void gemm_argmin_kernel(
    const float* __restrict__ X, const unsigned short* __restrict__ EhW,
    const float* __restrict__ esq, const float* __restrict__ Ef,
    int* __restrict__ nmin, int* __restrict__ counts, float* __restrict__ zq,
    double* __restrict__ sums) {
  __shared__ __align__(16) unsigned short sX[2][8][256][8];  // 65536 B persistent X

  const int tid  = threadIdx.x;
  const int lane = tid & 63, w = tid >> 6;
  const int lrow = lane & 15;
  const int qidx = lane >> 4;
  const int rowbase = (w >> 1) * 32;   // 2x2 wave grid: 32 rows x 64 cols each
  const int colb    = (w & 1) * 64;
  const int bm0 = (int)blockIdx.x * BM;

  // ---- prologue: load X f32, convert hi/lo, swizzled LDS writes, xsq partial ----
  {
    const int row = tid >> 2, p = tid & 3;     // 4 threads/row, 64 cols each
    const float* xp = X + (size_t)(bm0 + row) * DDIM + p * 64;
    float part = 0.f;
#pragma unroll
    for (int j = 0; j < 8; ++j) {
      const float4 a = *(const float4*)(xp + j * 8);
      const float4 b = *(const float4*)(xp + j * 8 + 4);
      float f[8] = {a.x, a.y, a.z, a.w, b.x, b.y, b.z, b.w};
      unsigned short hh[8], ll[8];
#pragma unroll
      for (int m = 0; m < 8; ++m) {
        hh[m] = f2h(f[m]);
        ll[m] = f2h(f[m] - h2f(hh[m]));
        part += f[m] * f[m];
      }
      const int kcc = p * 2 + (j >> 2);
      const int ch  = (row << 2) | ((j & 3) ^ ((row >> 1) & 3));
      *(uint4*)&sX[0][kcc][ch][0] = *(const uint4*)hh;
      *(uint4*)&sX[1][kcc][ch][0] = *(const uint4*)ll;
    }
#pragma unroll
    for (int o = 32; o > 0; o >>= 1) part += __shfl_down(part, o);
    if (lane == 0)
      atomicAdd(&sums[8 + (((int)blockIdx.x * 4 + w) & 63)], (double)part);
  }

  float rbest[8];
  int   ridx[8];
#pragma unroll
  for (int i = 0; i < 8; ++i) { rbest[i] = 3.4e38f; ridx[i] = 0; }

  // per-thread fragment LDS chunk indices (fixed across steps)
  int ra[2];
#pragma unroll
  for (int t = 0; t < 2; ++t) {
    const int m = rowbase + t * 16 + lrow;
    ra[t] = (m << 2) | (qidx ^ ((m >> 1) & 3));
  }
  // per-lane global B base pointers (E-hi, L2-resident)
  const unsigned short* bp[4];
#pragma unroll
  for (int t = 0; t < 4; ++t)
    bp[t] = EhW + (size_t)(colb + t * 16 + lrow) * DDIM + qidx * 8;

  __syncthreads();   // sX fully written; read-only from here: no loop barriers

  for (int nt = 0; nt < 8; ++nt) {
    f32x4 acc[2][4];
#pragma unroll
    for (int i = 0; i < 2; ++i)
#pragma unroll
      for (int j = 0; j < 4; ++j) acc[i][j] = (f32x4){0.f, 0.f, 0.f, 0.f};

    const size_t ntoff = (size_t)nt * BN * DDIM;
#pragma unroll
    for (int kcc = 0; kcc < 8; ++kcc) {
      half8 af0[2], af1[2], bfr[4];
#pragma unroll
      for (int t = 0; t < 4; ++t)
        bfr[t] = *(const half8*)(bp[t] + ntoff + kcc * 32);
#pragma unroll
      for (int t = 0; t < 2; ++t) {
        af0[t] = *(const half8*)&sX[0][kcc][ra[t]][0];
        af1[t] = *(const half8*)&sX[1][kcc][ra[t]][0];
      }
#pragma unroll
      for (int tr = 0; tr < 2; ++tr)
#pragma unroll
        for (int tc = 0; tc < 4; ++tc)
          acc[tr][tc] = __builtin_amdgcn_mfma_f32_16x16x32_f16(
              af0[tr], bfr[tc], acc[tr][tc], 0, 0, 0);
#pragma unroll
      for (int tr = 0; tr < 2; ++tr)
#pragma unroll
        for (int tc = 0; tc < 4; ++tc)
          acc[tr][tc] = __builtin_amdgcn_mfma_f32_16x16x32_f16(
              af1[tr], bfr[tc], acc[tr][tc], 0, 0, 0);
    }
    // epilogue: argmin update (registers only)
#pragma unroll
    for (int tc = 0; tc < 4; ++tc) {
      const int col = nt * BN + colb + tc * 16 + lrow;
      const float eq = esq[col];
#pragma unroll
      for (int tr = 0; tr < 2; ++tr)
#pragma unroll
        for (int rr = 0; rr < 4; ++rr) {
          float d = eq - 2.0f * acc[tr][tc][rr];
          const int slot = tr * 4 + rr;
          if (d < rbest[slot]) { rbest[slot] = d; ridx[slot] = col; }
        }
    }
  }

  __syncthreads();   // all waves done reading sX; reuse as scratch
  float* cdd = (float*)&sX[0][0][0][0];     // [2][64]
  int*   cdi = (int*)(cdd + 128);           // [2][64]
  int*   snm = cdi + 128;                   // [64]
  int*   h   = snm + 64;                    // [1024]

#pragma unroll
  for (int i = 0; i < 4; ++i) h[tid + i * 256] = 0;

#pragma unroll
  for (int slot = 0; slot < 8; ++slot) {
    float bd = rbest[slot];
    int   bi = ridx[slot];
#pragma unroll
    for (int off = 1; off < 16; off <<= 1) {
      float od = __shfl_xor(bd, off, 64);
      int   oi = __shfl_xor(bi, off, 64);
      if (od < bd || (od == bd && oi < bi)) { bd = od; bi = oi; }
    }
    if (lrow == 0) {
      const int row = rowbase + (slot >> 2) * 16 + (lane >> 4) * 4 + (slot & 3);
      cdd[(w & 1) * 64 + row] = bd;
      cdi[(w & 1) * 64 + row] = bi;
    }
  }
  __syncthreads();
  if (tid < BM) {
    float d0 = cdd[tid], d1 = cdd[64 + tid];
    int   i0 = cdi[tid], i1 = cdi[64 + tid];
    int bi = (d1 < d0 || (d1 == d0 && i1 < i0)) ? i1 : i0;
    nmin[bm0 + tid] = bi;
    snm[tid] = bi;
    atomicAdd(&h[bi], 1);
  }
  __syncthreads();
#pragma unroll
  for (int i = 0; i < 4; ++i) {
    int v = h[tid + i * 256];
    if (v) atomicAdd(&counts[tid + i * 256], v);
  }
  // ---- fused zq gather: wave w -> rows [w*16, w*16+16). E is L2-resident. ----
  const int r0 = w * 16;
#pragma unroll 4
  for (int r = 0; r < 16; ++r) {
    const int k = snm[r0 + r];
    const float4 v = *(const float4*)(Ef + (size_t)k * DDIM + lane * 4);
    *(float4*)(zq + (size_t)(bm0 + r0 + r) * DDIM + lane * 4) = v;
  }
}

// ---------------- scan ----------------
__global__ __launch_bounds__(1024) void scan_kernel(
    const int* __restrict__ counts, int* __restrict__ cur) {
  __shared__ int tmp[KEMB];
  int tid = threadIdx.x;
  int v = counts[tid];
  tmp[tid] = v;
  __syncthreads();
  for (int off = 1; off < 1024; off <<= 1) {
    int u = (tid >= off) ? tmp[tid - off] : 0;
    __syncthreads();
    tmp[tid] += u;
    __syncthreads();
  }
  cur[tid] = tmp[tid] - v;
}

// ---------------- scatter: counting-sort row ids by k ----------------
__global__ __launch_bounds__(1024) void scatter_kernel(
    const int* __restrict__ nm, int* __restrict__ cur,
    int* __restrict__ rows) {
  __shared__ int lcnt[KEMB], lbase[KEMB], lrank[KEMB];
  int tid = threadIdx.x;
  lcnt[tid] = 0; lrank[tid] = 0;
  __syncthreads();
  int b = blockIdx.x * 1024 + tid;
  int k = nm[b];
  atomicAdd(&lcnt[k], 1);
  __syncthreads();
  if (lcnt[tid] > 0) lbase[tid] = atomicAdd(&cur[tid], lcnt[tid]);
  __syncthreads();
  int r = atomicAdd(&lrank[k], 1);
  rows[lbase[k] + r] = b;
}

// ---------------- sxsum: segment-sum sorted chunks into SX (32 rows/block) ------
__global__ __launch_bounds__(256) void sxsum_kernel(
    const int* __restrict__ rows, const int* __restrict__ nm,
    const float* __restrict__ X, float* __restrict__ SX) {
  __shared__ int sb[32], sk[32];
  int tid = threadIdx.x;
  int p0 = blockIdx.x * 32;
  if (tid < 32) sb[tid] = rows[p0 + tid];
  __syncthreads();
  if (tid < 32) sk[tid] = nm[sb[tid]];
  __syncthreads();
  float acc = 0.f;
  int kprev = sk[0];
  for (int i = 0; i < 32; ++i) {
    int k = sk[i];
    if (k != kprev) {
      atomicAdd(&SX[(size_t)kprev * DDIM + tid], acc);
      acc = 0.f;
      kprev = k;
    }
    acc += X[(size_t)sb[i] * DDIM + tid];
  }
  atomicAdd(&SX[(size_t)kprev * DDIM + tid], acc);
}

// ---------------- stencil: new_embeddings + loss partials ----------------
__global__ __launch_bounds__(256) void stencil_kernel(
    const float* __restrict__ E, const float* __restrict__ SX,
    const int* __restrict__ counts, const float* __restrict__ esq,
    double* __restrict__ sums, float* __restrict__ out) {
  __shared__ float redc[256], reds[256];
  int k = blockIdx.x, t = threadIdx.x;
  int kx = k >> 5, ky = k & 31;
  int j1 = (kx >= 1)  ? k - 32 : k;
  int j2 = (kx <= 30) ? k + 32 : k;
  int j3 = (ky >= 1)  ? k - 1  : k;
  int j4 = (ky <= 30) ? k + 1  : k;
  int fU = (kx < 31) ? k + 32 : k;
  int fD = (kx > 0)  ? k - 32 : k;
  int fL = (ky > 0)  ? k - 1  : k;
  int fR = (ky < 31) ? k + 1  : k;

  float e   = E[(size_t)k * DDIM + t];
  float sxk = SX[(size_t)k * DDIM + t];
  float Tk = sxk - (float)counts[k] * e;
  float T1 = SX[(size_t)j1 * DDIM + t] - (float)counts[j1] * E[(size_t)j1 * DDIM + t];
  float T2 = SX[(size_t)j2 * DDIM + t] - (float)counts[j2] * E[(size_t)j2 * DDIM + t];
  float T3 = SX[(size_t)j3 * DDIM + t] - (float)counts[j3] * E[(size_t)j3 * DDIM + t];
  float T4 = SX[(size_t)j4 * DDIM + t] - (float)counts[j4] * E[(size_t)j4 * DDIM + t];
  float v = e + LRC * Tk + 0.5f * LRC * (T1 + T2 + T3 + T4);
  out[(size_t)B_ROWS * DDIM + 2 + (size_t)k * DDIM + t] = v;

  float eU = E[(size_t)fU * DDIM + t], eD = E[(size_t)fD * DDIM + t];
  float eL = E[(size_t)fL * DDIM + t], eR = E[(size_t)fR * DDIM + t];
  float cp = -2.f * sxk * e;
  float sp = -2.f * sxk * (eU + eD + eL + eR);
  if (t == 0) {
    float ck = (float)counts[k];
    cp += ck * esq[k];
    sp += ck * (esq[fU] + esq[fD] + esq[fL] + esq[fR]);
  }
  redc[t] = cp; reds[t] = sp;
  __syncthreads();
  for (int s = 128; s > 0; s >>= 1) {
    if (t < s) { redc[t] += redc[t + s]; reds[t] += reds[t + s]; }
    __syncthreads();
  }
  if (t == 0) {
    atomicAdd(&sums[1], (double)redc[0]);
    atomicAdd(&sums[2], (double)reds[0]);
  }
}

// ---------------- finalize losses ----------------
__global__ void finalize_kernel(const double* __restrict__ sums,
                                float* __restrict__ out) {
  double xsq = 0.0;
  for (int s = 0; s < 64; ++s) xsq += sums[8 + s];
  out[(size_t)B_ROWS * DDIM]     = (float)((xsq + sums[1]) / ((double)B_ROWS * DDIM));
  out[(size_t)B_ROWS * DDIM + 1] =
      (float)((4.0 * xsq + sums[2]) / ((double)B_ROWS * 4.0 * DDIM));
}

extern "C" void kernel_launch(void* const* d_in, const int* in_sizes, int n_in,
                              void* d_out, int out_size, void* d_ws, size_t ws_size,
                              hipStream_t stream) {
  const float* X = (const float*)d_in[0];
  const float* E = (const float*)d_in[1];
  float* out = (float*)d_out;
  char* ws = (char*)d_ws;

  float*          SX   = (float*)(ws + SX_OFF);
  int*            cnts = (int*)(ws + CNT_OFF);
  double*         sums = (double*)(ws + SUMS_OFF);
  float*          esq  = (float*)(ws + ESQ_OFF);
  int*            cur  = (int*)(ws + CUR_OFF);
  int*            nm   = (int*)(ws + NMIN_OFF);
  int*            rows = (int*)(ws + ROWS_OFF);
  unsigned short* EhW  = (unsigned short*)(ws + EH_OFF);

  hipMemsetAsync(ws, 0, ESQ_OFF, stream);   // SX + counts + sums

  convert_kernel<<<KEMB * (DDIM / 8) / 256, 256, 0, stream>>>(E, EhW, esq);
  gemm_argmin_kernel<<<B_ROWS / BM, 256, 0, stream>>>(X, EhW, esq, E, nm, cnts, out,
                                                      sums);
  scan_kernel<<<1, 1024, 0, stream>>>(cnts, cur);
  scatter_kernel<<<B_ROWS / 1024, 1024, 0, stream>>>(nm, cur, rows);
  sxsum_kernel<<<B_ROWS / 32, 256, 0, stream>>>(rows, nm, X, SX);
  stencil_kernel<<<KEMB, 256, 0, stream>>>(E, SX, cnts, esq, sums, out);
  finalize_kernel<<<1, 1, 0, stream>>>(sums, out);
}

// Round 5
// 250.338 us; speedup vs baseline: 1.1932x; 1.1932x over previous
//
#include <hip/hip_runtime.h>

#define B_ROWS 65536
#define DDIM   256
#define KEMB   1024
#define LRC    0.05f
#define BM 64
#define BN 128

typedef __attribute__((ext_vector_type(8))) _Float16 half8;
typedef __attribute__((ext_vector_type(4))) float f32x4;

// ---- workspace layout (bytes) ----
#define SX_OFF    0u            // 1 MB fp32 [K][D]
#define CNT_OFF   1048576u      // 4 KB int [K]
#define SUMS_OFF  1052672u      // 640 B: [1]=commit,[2]=som,[8..71]=xsq slots
#define ESQ_OFF   1053312u      // 4 KB fp32 [K]
#define CUR_OFF   1057408u      // 4 KB int [K]
#define NMIN_OFF  1061504u      // int [B] = 256 KB
#define ROWS_OFF  1585792u      // 256 KB int [B]
#define EH_OFF    1847936u      // 512 KB f16 [K][D]

static __device__ __forceinline__ unsigned short f2h(float f) {
  _Float16 h = (_Float16)f;
  return *(unsigned short*)&h;
}
static __device__ __forceinline__ float h2f(unsigned short u) {
  _Float16 h = *(_Float16*)&u;
  return (float)h;
}
static __device__ __forceinline__ void glds16(const void* g, void* l) {
  __builtin_amdgcn_global_load_lds(
      (const __attribute__((address_space(1))) unsigned int*)g,
      (__attribute__((address_space(3))) unsigned int*)l, 16, 0, 0);
}

// ---------------- convert: E->Eh f16 + esq (X conversion fused into gemm) ----
__global__ __launch_bounds__(256) void convert_kernel(
    const float* __restrict__ E, unsigned short* __restrict__ Eh,
    float* __restrict__ esq) {
  size_t i = (size_t)blockIdx.x * 256 + threadIdx.x;
  size_t off = i * 8;
  const float4 v0 = *(const float4*)(E + off);
  const float4 v1 = *(const float4*)(E + off + 4);
  float f[8] = {v0.x, v0.y, v0.z, v0.w, v1.x, v1.y, v1.z, v1.w};
  unsigned short h[8];
  float part = 0.f;
#pragma unroll
  for (int j = 0; j < 8; ++j) {
    h[j] = f2h(f[j]);
    part += f[j] * f[j];
  }
  *(uint4*)(Eh + off) = *(const uint4*)h;
  float s = part;
  for (int o = 16; o > 0; o >>= 1) s += __shfl_down(s, o, 32);
  if ((threadIdx.x & 31) == 0) esq[i >> 5] = s;
}

// ---------------- A: X-persistent-LDS dist-GEMM (round-3 loop) + fused convert --
// Round-4 post-mortem: B-from-global regressed (L1/L2 latency+throughput on the
// critical path, 105->165us); the fused X convert was worth ~40us but its
// ds_write pattern was 4-way bank-conflicted (same-row lanes shared bank sets).
// Round 5: round-3 K-loop VERBATIM (sE glds16 dbuf, per-step barrier, 105us
// measured) + prologue converts X f32->hi/lo f16 with LANE-LINEAR ds_write_b128
// (thread of linear chunk c writes byte c*16 — glds16's measured-conflict-free
// pattern; hi->tile0, lo->tile1 at +32KB). Deletes the 40us convert-X pass and
// the Xhl HBM round-trip. Bit-identical math: same f2h split, same E bytes,
// same MFMA order, same argmin tie-breaks.
__global__ __launch_bounds__(256, 2) void gemm_argmin_kernel(
    const float* __restrict__ X, const unsigned short* __restrict__ EhW,
    const float* __restrict__ esq, const float* __restrict__ Ef,
    int* __restrict__ nmin, int* __restrict__ counts, float* __restrict__ zq,
    double* __restrict__ sums) {
  __shared__ __align__(16) unsigned short sX[2][8][256][8];  // 65536 B persistent X
  __shared__ __align__(16) unsigned short sE[2][512][8];     // 16384 B E dbuf

  const int tid  = threadIdx.x;
  const int lane = tid & 63, w = tid >> 6;
  const int lrow = lane & 15;
  const int qidx = lane >> 4;
  const int rowbase = (w >> 1) * 32;   // 2x2 wave grid: 32 rows x 64 cols each
  const int colb    = (w & 1) * 64;
  const int bm0 = (int)blockIdx.x * BM;

  // per-thread E-stage invariants (E tile = BN x 32k = 512 chunks)
  int ec_row[2], ec_q8[2];
#pragma unroll
  for (int j = 0; j < 2; ++j) {
    const int c = j * 256 + tid;
    ec_row[j] = c >> 2;
    ec_q8[j]  = ((c & 3) ^ ((ec_row[j] >> 1) & 3)) * 8;
  }

  // ---- stage E(step0) first so its L2 latency hides under the convert ----
#pragma unroll
  for (int j = 0; j < 2; ++j)
    glds16(EhW + (size_t)ec_row[j] * DDIM + ec_q8[j], (char*)&sE[0][j * 256 + tid][0]);

  // ---- prologue: X f32 -> hi/lo f16, lane-linear conflict-free ds_writes ----
  {
    float part = 0.f;
#pragma unroll
    for (int it = 0; it < 8; ++it) {
      const int c   = it * 256 + tid;        // linear tile-0 chunk id
      const int kcc = c >> 8;
      const int cc  = c & 255;
      const int row = cc >> 2;
      const int q   = (cc & 3) ^ ((row >> 1) & 3);
      const float* xp = X + (size_t)(bm0 + row) * DDIM + kcc * 32 + q * 8;
      const float4 a = *(const float4*)xp;
      const float4 b = *(const float4*)(xp + 4);
      float f[8] = {a.x, a.y, a.z, a.w, b.x, b.y, b.z, b.w};
      unsigned short hh[8], ll[8];
#pragma unroll
      for (int m = 0; m < 8; ++m) {
        hh[m] = f2h(f[m]);
        ll[m] = f2h(f[m] - h2f(hh[m]));
        part += f[m] * f[m];
      }
      *(uint4*)((char*)sX + (size_t)c * 16)          = *(const uint4*)hh;  // tile 0
      *(uint4*)((char*)sX + (size_t)(c + 2048) * 16) = *(const uint4*)ll;  // tile 1
    }
#pragma unroll
    for (int o = 32; o > 0; o >>= 1) part += __shfl_down(part, o);
    if (lane == 0)
      atomicAdd(&sums[8 + (((int)blockIdx.x * 4 + w) & 63)], (double)part);
  }

  float rbest[8];
  int   ridx[8];
#pragma unroll
  for (int i = 0; i < 8; ++i) { rbest[i] = 3.4e38f; ridx[i] = 0; }

  // per-thread fragment LDS chunk indices (fixed across steps)
  int ra[2], rb[4];
#pragma unroll
  for (int t = 0; t < 2; ++t) {
    const int m = rowbase + t * 16 + lrow;
    ra[t] = (m << 2) | (qidx ^ ((m >> 1) & 3));
  }
#pragma unroll
  for (int t = 0; t < 4; ++t) {
    const int n = colb + t * 16 + lrow;
    rb[t] = (n << 2) | (qidx ^ ((n >> 1) & 3));
  }

  __syncthreads();   // sX written by all waves + E0 drained (vmcnt0+lgkm0)

  for (int nt = 0; nt < 8; ++nt) {
    f32x4 acc[2][4];
#pragma unroll
    for (int i = 0; i < 2; ++i)
#pragma unroll
      for (int j = 0; j < 4; ++j) acc[i][j] = (f32x4){0.f, 0.f, 0.f, 0.f};

#pragma unroll
    for (int kcc = 0; kcc < 8; ++kcc) {
      const int s   = nt * 8 + kcc;
      const int cur = s & 1;
      // stage next E tile into the other buffer BEFORE compute (hides latency)
      if (s < 63) {
        const int ns = s + 1;
        const int nnt = ns >> 3, nk = ns & 7;
#pragma unroll
        for (int j = 0; j < 2; ++j) {
          const int c = j * 256 + tid;
          glds16(EhW + (size_t)(nnt * BN + ec_row[j]) * DDIM + nk * 32 + ec_q8[j],
                 (char*)&sE[cur ^ 1][c][0]);
        }
      }
      half8 af0[2], af1[2], bfr[4];
#pragma unroll
      for (int t = 0; t < 2; ++t) {
        af0[t] = *(const half8*)&sX[0][kcc][ra[t]][0];
        af1[t] = *(const half8*)&sX[1][kcc][ra[t]][0];
      }
#pragma unroll
      for (int t = 0; t < 4; ++t) bfr[t] = *(const half8*)&sE[cur][rb[t]][0];
#pragma unroll
      for (int tr = 0; tr < 2; ++tr)
#pragma unroll
        for (int tc = 0; tc < 4; ++tc)
          acc[tr][tc] = __builtin_amdgcn_mfma_f32_16x16x32_f16(
              af0[tr], bfr[tc], acc[tr][tc], 0, 0, 0);
#pragma unroll
      for (int tr = 0; tr < 2; ++tr)
#pragma unroll
        for (int tc = 0; tc < 4; ++tc)
          acc[tr][tc] = __builtin_amdgcn_mfma_f32_16x16x32_f16(
              af1[tr], bfr[tc], acc[tr][tc], 0, 0, 0);
      // single barrier/step: protects E dbuf WAR + drains own stage (vmcnt 0)
      __syncthreads();
    }
    // epilogue: argmin update (registers only; safe across the barrier)
#pragma unroll
    for (int tc = 0; tc < 4; ++tc) {
      const int col = nt * BN + colb + tc * 16 + lrow;
      const float eq = esq[col];
#pragma unroll
      for (int tr = 0; tr < 2; ++tr)
#pragma unroll
        for (int rr = 0; rr < 4; ++rr) {
          float d = eq - 2.0f * acc[tr][tc][rr];
          const int slot = tr * 4 + rr;
          if (d < rbest[slot]) { rbest[slot] = d; ridx[slot] = col; }
        }
    }
  }

  // ---- block-local argmin reduce (scratch in sE), fused hist (scratch in sX) --
  float* cdd = (float*)&sE[0][0][0];        // [2][64]
  int*   cdi = (int*)(cdd + 128);           // [2][64]
  int*   snm = cdi + 128;                   // [64]
  int*   h   = (int*)&sX[0][0][0][0];       // [1024]

#pragma unroll
  for (int i = 0; i < 4; ++i) h[tid + i * 256] = 0;

#pragma unroll
  for (int slot = 0; slot < 8; ++slot) {
    float bd = rbest[slot];
    int   bi = ridx[slot];
#pragma unroll
    for (int off = 1; off < 16; off <<= 1) {
      float od = __shfl_xor(bd, off, 64);
      int   oi = __shfl_xor(bi, off, 64);
      if (od < bd || (od == bd && oi < bi)) { bd = od; bi = oi; }
    }
    if (lrow == 0) {
      const int row = rowbase + (slot >> 2) * 16 + (lane >> 4) * 4 + (slot & 3);
      cdd[(w & 1) * 64 + row] = bd;
      cdi[(w & 1) * 64 + row] = bi;
    }
  }
  __syncthreads();
  if (tid < BM) {
    float d0 = cdd[tid], d1 = cdd[64 + tid];
    int   i0 = cdi[tid], i1 = cdi[64 + tid];
    int bi = (d1 < d0 || (d1 == d0 && i1 < i0)) ? i1 : i0;
    nmin[bm0 + tid] = bi;
    snm[tid] = bi;
    atomicAdd(&h[bi], 1);
  }
  __syncthreads();
#pragma unroll
  for (int i = 0; i < 4; ++i) {
    int v = h[tid + i * 256];
    if (v) atomicAdd(&counts[tid + i * 256], v);
  }
  // ---- fused zq gather: wave w -> rows [w*16, w*16+16). E is L2-resident. ----
  const int r0 = w * 16;
#pragma unroll 4
  for (int r = 0; r < 16; ++r) {
    const int k = snm[r0 + r];
    const float4 v = *(const float4*)(Ef + (size_t)k * DDIM + lane * 4);
    *(float4*)(zq + (size_t)(bm0 + r0 + r) * DDIM + lane * 4) = v;
  }
}

// ---------------- scan ----------------
__global__ __launch_bounds__(1024) void scan_kernel(
    const int* __restrict__ counts, int* __restrict__ cur) {
  __shared__ int tmp[KEMB];
  int tid = threadIdx.x;
  int v = counts[tid];
  tmp[tid] = v;
  __syncthreads();
  for (int off = 1; off < 1024; off <<= 1) {
    int u = (tid >= off) ? tmp[tid - off] : 0;
    __syncthreads();
    tmp[tid] += u;
    __syncthreads();
  }
  cur[tid] = tmp[tid] - v;
}

// ---------------- scatter: counting-sort row ids by k ----------------
__global__ __launch_bounds__(1024) void scatter_kernel(
    const int* __restrict__ nm, int* __restrict__ cur,
    int* __restrict__ rows) {
  __shared__ int lcnt[KEMB], lbase[KEMB], lrank[KEMB];
  int tid = threadIdx.x;
  lcnt[tid] = 0; lrank[tid] = 0;
  __syncthreads();
  int b = blockIdx.x * 1024 + tid;
  int k = nm[b];
  atomicAdd(&lcnt[k], 1);
  __syncthreads();
  if (lcnt[tid] > 0) lbase[tid] = atomicAdd(&cur[tid], lcnt[tid]);
  __syncthreads();
  int r = atomicAdd(&lrank[k], 1);
  rows[lbase[k] + r] = b;
}

// ---------------- sxsum: segment-sum sorted chunks into SX (32 rows/block) ------
__global__ __launch_bounds__(256) void sxsum_kernel(
    const int* __restrict__ rows, const int* __restrict__ nm,
    const float* __restrict__ X, float* __restrict__ SX) {
  __shared__ int sb[32], sk[32];
  int tid = threadIdx.x;
  int p0 = blockIdx.x * 32;
  if (tid < 32) sb[tid] = rows[p0 + tid];
  __syncthreads();
  if (tid < 32) sk[tid] = nm[sb[tid]];
  __syncthreads();
  float acc = 0.f;
  int kprev = sk[0];
  for (int i = 0; i < 32; ++i) {
    int k = sk[i];
    if (k != kprev) {
      atomicAdd(&SX[(size_t)kprev * DDIM + tid], acc);
      acc = 0.f;
      kprev = k;
    }
    acc += X[(size_t)sb[i] * DDIM + tid];
  }
  atomicAdd(&SX[(size_t)kprev * DDIM + tid], acc);
}

// ---------------- stencil: new_embeddings + loss partials ----------------
__global__ __launch_bounds__(256) void stencil_kernel(
    const float* __restrict__ E, const float* __restrict__ SX,
    const int* __restrict__ counts, const float* __restrict__ esq,
    double* __restrict__ sums, float* __restrict__ out) {
  __shared__ float redc[256], reds[256];
  int k = blockIdx.x, t = threadIdx.x;
  int kx = k >> 5, ky = k & 31;
  int j1 = (kx >= 1)  ? k - 32 : k;
  int j2 = (kx <= 30) ? k + 32 : k;
  int j3 = (ky >= 1)  ? k - 1  : k;
  int j4 = (ky <= 30) ? k + 1  : k;
  int fU = (kx < 31) ? k + 32 : k;
  int fD = (kx > 0)  ? k - 32 : k;
  int fL = (ky > 0)  ? k - 1  : k;
  int fR = (ky < 31) ? k + 1  : k;

  float e   = E[(size_t)k * DDIM + t];
  float sxk = SX[(size_t)k * DDIM + t];
  float Tk = sxk - (float)counts[k] * e;
  float T1 = SX[(size_t)j1 * DDIM + t] - (float)counts[j1] * E[(size_t)j1 * DDIM + t];
  float T2 = SX[(size_t)j2 * DDIM + t] - (float)counts[j2] * E[(size_t)j2 * DDIM + t];
  float T3 = SX[(size_t)j3 * DDIM + t] - (float)counts[j3] * E[(size_t)j3 * DDIM + t];
  float T4 = SX[(size_t)j4 * DDIM + t] - (float)counts[j4] * E[(size_t)j4 * DDIM + t];
  float v = e + LRC * Tk + 0.5f * LRC * (T1 + T2 + T3 + T4);
  out[(size_t)B_ROWS * DDIM + 2 + (size_t)k * DDIM + t] = v;

  float eU = E[(size_t)fU * DDIM + t], eD = E[(size_t)fD * DDIM + t];
  float eL = E[(size_t)fL * DDIM + t], eR = E[(size_t)fR * DDIM + t];
  float cp = -2.f * sxk * e;
  float sp = -2.f * sxk * (eU + eD + eL + eR);
  if (t == 0) {
    float ck = (float)counts[k];
    cp += ck * esq[k];
    sp += ck * (esq[fU] + esq[fD] + esq[fL] + esq[fR]);
  }
  redc[t] = cp; reds[t] = sp;
  __syncthreads();
  for (int s = 128; s > 0; s >>= 1) {
    if (t < s) { redc[t] += redc[t + s]; reds[t] += reds[t + s]; }
    __syncthreads();
  }
  if (t == 0) {
    atomicAdd(&sums[1], (double)redc[0]);
    atomicAdd(&sums[2], (double)reds[0]);
  }
}

// ---------------- finalize losses ----------------
__global__ void finalize_kernel(const double* __restrict__ sums,
                                float* __restrict__ out) {
  double xsq = 0.0;
  for (int s = 0; s < 64; ++s) xsq += sums[8 + s];
  out[(size_t)B_ROWS * DDIM]     = (float)((xsq + sums[1]) / ((double)B_ROWS * DDIM));
  out[(size_t)B_ROWS * DDIM + 1] =
      (float)((4.0 * xsq + sums[2]) / ((double)B_ROWS * 4.0 * DDIM));
}

extern "C" void kernel_launch(void* const* d_in, const int* in_sizes, int n_in,
                              void* d_out, int out_size, void* d_ws, size_t ws_size,
                              hipStream_t stream) {
  const float* X = (const float*)d_in[0];
  const float* E = (const float*)d_in[1];
  float* out = (float*)d_out;
  char* ws = (char*)d_ws;

  float*          SX   = (float*)(ws + SX_OFF);
  int*            cnts = (int*)(ws + CNT_OFF);
  double*         sums = (double*)(ws + SUMS_OFF);
  float*          esq  = (float*)(ws + ESQ_OFF);
  int*            cur  = (int*)(ws + CUR_OFF);
  int*            nm   = (int*)(ws + NMIN_OFF);
  int*            rows = (int*)(ws + ROWS_OFF);
  unsigned short* EhW  = (unsigned short*)(ws + EH_OFF);

  hipMemsetAsync(ws, 0, ESQ_OFF, stream);   // SX + counts + sums

  convert_kernel<<<KEMB * (DDIM / 8) / 256, 256, 0, stream>>>(E, EhW, esq);
  gemm_argmin_kernel<<<B_ROWS / BM, 256, 0, stream>>>(X, EhW, esq, E, nm, cnts, out,
                                                      sums);
  scan_kernel<<<1, 1024, 0, stream>>>(cnts, cur);
  scatter_kernel<<<B_ROWS / 1024, 1024, 0, stream>>>(nm, cur, rows);
  sxsum_kernel<<<B_ROWS / 32, 256, 0, stream>>>(rows, nm, X, SX);
  stencil_kernel<<<KEMB, 256, 0, stream>>>(E, SX, cnts, esq, sums, out);
  finalize_kernel<<<1, 1, 0, stream>>>(sums, out);
}